// Round 4
// baseline (1378.930 us; speedup 1.0000x reference)
//
#include <hip/hip_runtime.h>
#include <cstdint>

// Problem dims (fixed by reference): B=4, S=2048 -> M=8192, K=4096, N=16384
#define MDIM 8192
#define KDIM 4096
#define NDIM 16384

// GEMM geometry: 256x256 tile, 512 thr / 8 waves (2M x 4N), BK=64 bytes,
// 4-deep global_load_lds pipeline, counted vmcnt (T4), T2 swizzle, T5 setprio,
// T1 XCD swizzle.
// Round 4: REGISTER-PIPELINED FRAGMENTS. Each MFMA cluster consumes frags
// read one phase earlier, so LDS delivery overlaps MFMA instead of
// serializing (rounds 1-3 measured 33-35% MfmaUtil = MFMA+LDS+sync fully
// serial). Barriers 4->2 per K-tile; no asm lgkmcnt(0)/sched_barrier
// (compiler emits counted lgkmcnt).
#define BM 256
#define BN 256
#define BKB 64              // K-bytes per tile step
#define NT (KDIM / BKB)     // 64 K-tiles

typedef int v4i __attribute__((ext_vector_type(4)));

__device__ __forceinline__ void gload_lds16(const void* g, void* l) {
    __builtin_amdgcn_global_load_lds(
        (const __attribute__((address_space(1))) int*)g,
        (__attribute__((address_space(3))) int*)l, 16, 0, 0);
}

// ---------------------------------------------------------------------------
// Kernel 1: pack W int32 [N,K] -> int8 [N,K].
__global__ __launch_bounds__(256) void conv_w(const int4* __restrict__ w,
                                              int* __restrict__ wq) {
    int g = blockIdx.x * 256 + threadIdx.x;
    int4 v = w[g];
    unsigned p = (unsigned)(v.x & 255) | ((unsigned)(v.y & 255) << 8) |
                 ((unsigned)(v.z & 255) << 16) | ((unsigned)(v.w & 255) << 24);
    wq[g] = (int)p;
}

// ---------------------------------------------------------------------------
// Kernel 2: per-row absmax quantize of x [M,K] fp32 -> int8 + scale_x[M].
__global__ __launch_bounds__(256) void quant_rows(const float* __restrict__ x,
                                                  int* __restrict__ xq32,
                                                  float* __restrict__ sx) {
    const int row = blockIdx.x;
    const int t = threadIdx.x;
    const float4* xr = (const float4*)(x + (size_t)row * KDIM);

    float4 v[4];
    float amax = 0.f;
#pragma unroll
    for (int p = 0; p < 4; ++p) {
        v[p] = xr[p * 256 + t];
        amax = fmaxf(amax, fmaxf(fmaxf(fabsf(v[p].x), fabsf(v[p].y)),
                                 fmaxf(fabsf(v[p].z), fabsf(v[p].w))));
    }
#pragma unroll
    for (int off = 32; off > 0; off >>= 1)
        amax = fmaxf(amax, __shfl_down(amax, off));
    __shared__ float wmax[4];
    int wave = t >> 6, lane = t & 63;
    if (lane == 0) wmax[wave] = amax;
    __syncthreads();
    float m = fmaxf(fmaxf(wmax[0], wmax[1]), fmaxf(wmax[2], wmax[3]));

    float inv = (m > 0.f) ? 127.f / m : 0.f;
    if (t == 0) {
        float s = m / 127.f;
        sx[row] = (s == 0.f) ? 1.f : s;
    }

    int* out = xq32 + (size_t)row * (KDIM / 4);
#pragma unroll
    for (int p = 0; p < 4; ++p) {
        int q0 = (int)rintf(v[p].x * inv); q0 = max(-127, min(127, q0));
        int q1 = (int)rintf(v[p].y * inv); q1 = max(-127, min(127, q1));
        int q2 = (int)rintf(v[p].z * inv); q2 = max(-127, min(127, q2));
        int q3 = (int)rintf(v[p].w * inv); q3 = max(-127, min(127, q3));
        unsigned pk = (unsigned)(q0 & 255) | ((unsigned)(q1 & 255) << 8) |
                      ((unsigned)(q2 & 255) << 16) | ((unsigned)(q3 & 255) << 24);
        out[p * 256 + t] = (int)pk;
    }
}

// ---------------------------------------------------------------------------
// Kernel 3: int8 GEMM 256x256, register-pipelined fragment schedule.
__global__ __launch_bounds__(512, 2) void gemm_i8(const signed char* __restrict__ xq,
                                                  const signed char* __restrict__ wq,
                                                  const float* __restrict__ sx,
                                                  const float* __restrict__ scale,
                                                  const float* __restrict__ bias,
                                                  float* __restrict__ y) {
    // 4 buffers x (A 16KB + B 16KB) = 128 KiB -> 1 block/CU, 2 waves/SIMD
    __shared__ __align__(16) signed char lds_a[4][BM * BKB];
    __shared__ __align__(16) signed char lds_b[4][BN * BKB];

    const int tid  = threadIdx.x;
    const int lane = tid & 63;
    const int wave = tid >> 6;           // 0..7
    const int l16  = lane & 15;
    const int quad = lane >> 4;
    const int wm   = wave >> 2;          // 0..1  M-half
    const int wn   = wave & 3;           // 0..3  N-quarter

    // T1: bijective XCD-chunked swizzle (2048 blocks, 2048 % 8 == 0)
    int lin = blockIdx.y * gridDim.x + blockIdx.x;
    lin = (lin & 7) * ((MDIM / BM) * (NDIM / BN) / 8) + (lin >> 3);
    const int tileN = (lin & (NDIM / BN - 1)) * BN;
    const int tileM = (lin >> 6) * BM;

    // Staging: LDS linear dest for global_load_lds; global SOURCE column
    // pre-swizzled with the same involution the ds_read side applies.
    const int srow = tid >> 2;                                   // 0..127
    const int scol = ((tid & 3) << 4) ^ (((srow >> 1) & 3) << 4);
    const signed char* gA0 = xq + (size_t)(tileM + srow) * KDIM + scol;
    const signed char* gA1 = gA0 + (size_t)128 * KDIM;
    const signed char* gB0 = wq + (size_t)(tileN + srow) * KDIM + scol;
    const signed char* gB1 = gB0 + (size_t)128 * KDIM;
    const int lo = tid << 4;

    // ds_read addressing with the same XOR swizzle.
    const int rcol = (quad << 4) ^ (((l16 >> 1) & 3) << 4);
    const int aoff = (wm * 128 + l16) * BKB + rcol;
    const int boff = (wn * 64 + l16) * BKB + rcol;

    v4i acc[8][4] = {};
    v4i A0[4], B0[4], A1[4], B1[4];      // ping-pong current/next frag sets

#define STAGE_A(GOFF, BUF) do {                                               \
        gload_lds16(gA0 + (GOFF), &lds_a[BUF][lo]);                           \
        gload_lds16(gA1 + (GOFF), &lds_a[BUF][lo + 8192]); } while (0)
#define STAGE_B(GOFF, BUF) do {                                               \
        gload_lds16(gB0 + (GOFF), &lds_b[BUF][lo]);                           \
        gload_lds16(gB1 + (GOFF), &lds_b[BUF][lo + 8192]); } while (0)

#define VMW(N) asm volatile("s_waitcnt vmcnt(" #N ")" ::: "memory")

// One K-tile. BC_: this tile's LDS buffer (constant 0..3). CA_/CB_: frag set
// holding THIS tile's af/bf (read one phase ago). NA_/NB_: frag set to fill
// with NEXT tile's af/bf. vg (A-half-1) is read at PhaseA start and consumed
// by PhaseB's MFMA -- covered by PhaseA's MFMA cluster.
#define TILE(BC_, CA_, CB_, NA_, NB_, DO_PF_, PFOFF_, DO_NEXT_, DO_SYNC_, VMN_) do { \
    v4i vg_[4];                                                               \
    /* PhaseA: read vg, issue A-prefetch, MFMA on CA x CB (no wait) */        \
    _Pragma("unroll")                                                         \
    for (int i_ = 0; i_ < 4; ++i_)                                            \
        vg_[i_] = *(const v4i*)(&lds_a[BC_][0] + aoff + (4 + i_) * 1024);     \
    if (DO_PF_) STAGE_A(PFOFF_, ((BC_) + 3) & 3);                             \
    __builtin_amdgcn_s_setprio(1);                                            \
    _Pragma("unroll")                                                         \
    for (int i_ = 0; i_ < 4; ++i_)                                            \
        _Pragma("unroll")                                                     \
        for (int j_ = 0; j_ < 4; ++j_)                                        \
            acc[i_][j_] = __builtin_amdgcn_mfma_i32_16x16x64_i8(              \
                CA_[i_], CB_[j_], acc[i_][j_], 0, 0, 0);                      \
    __builtin_amdgcn_s_setprio(0);                                            \
    /* PhaseB: retire next buffer's DMA, read next tile's frags, MFMA vg */   \
    if (DO_SYNC_) { VMW(VMN_); __builtin_amdgcn_s_barrier(); }                \
    if (DO_NEXT_) {                                                           \
        _Pragma("unroll")                                                     \
        for (int i_ = 0; i_ < 4; ++i_)                                        \
            NA_[i_] = *(const v4i*)(&lds_a[((BC_) + 1) & 3][0] + aoff + i_ * 1024); \
        _Pragma("unroll")                                                     \
        for (int j_ = 0; j_ < 4; ++j_)                                        \
            NB_[j_] = *(const v4i*)(&lds_b[((BC_) + 1) & 3][0] + boff + j_ * 1024); \
    }                                                                         \
    if (DO_PF_) STAGE_B(PFOFF_, ((BC_) + 3) & 3);                             \
    __builtin_amdgcn_s_setprio(1);                                            \
    _Pragma("unroll")                                                         \
    for (int i_ = 0; i_ < 4; ++i_)                                            \
        _Pragma("unroll")                                                     \
        for (int j_ = 0; j_ < 4; ++j_)                                        \
            acc[4 + i_][j_] = __builtin_amdgcn_mfma_i32_16x16x64_i8(          \
                vg_[i_], CB_[j_], acc[4 + i_][j_], 0, 0, 0);                  \
    __builtin_amdgcn_s_setprio(0);                                            \
    if (DO_SYNC_) __builtin_amdgcn_s_barrier();                               \
} while (0)

    // ---- prologue: stage tiles 0,1,2 (12 loads); tile0 ready at vmcnt(8);
    // then preload tile0's af/bf into the first frag set.
    STAGE_A((size_t)0 * BKB, 0); STAGE_B((size_t)0 * BKB, 0);
    STAGE_A((size_t)1 * BKB, 1); STAGE_B((size_t)1 * BKB, 1);
    STAGE_A((size_t)2 * BKB, 2); STAGE_B((size_t)2 * BKB, 2);
    VMW(8);
    __builtin_amdgcn_s_barrier();
#pragma unroll
    for (int i = 0; i < 4; ++i) {
        A0[i] = *(const v4i*)(&lds_a[0][0] + aoff + i * 1024);
        B0[i] = *(const v4i*)(&lds_b[0][0] + boff + i * 1024);
    }

    // ---- main loop: tiles 0..59, groups of 4 (buffer = tile&3, static).
    // Steady-state in-flight at VMW: t+1(4) + t+2(4) + t+3(A:2) -> VMW(6)
    // retires tile t+1 completely.
    for (int g = 0; g < 15; ++g) {
        const size_t kb = (size_t)g * 4 * BKB;
        TILE(0, A0, B0, A1, B1, true, kb + (size_t)3 * BKB, true, true, 6);
        TILE(1, A1, B1, A0, B0, true, kb + (size_t)4 * BKB, true, true, 6);
        TILE(2, A0, B0, A1, B1, true, kb + (size_t)5 * BKB, true, true, 6);
        TILE(3, A1, B1, A0, B0, true, kb + (size_t)6 * BKB, true, true, 6);
    }

    // ---- tail: tiles 60..63; vmcnt countdown 6 -> 4 -> 0.
    TILE(0, A0, B0, A1, B1, true, (size_t)63 * BKB, true, true, 6);
    TILE(1, A1, B1, A0, B0, false, 0, true, true, 4);
    TILE(2, A0, B0, A1, B1, false, 0, true, true, 0);
    TILE(3, A1, B1, A0, B0, false, 0, false, false, 0);

    // ---- epilogue: C/D layout col=l16, row=quad*4+r (shape-determined)
    float sxv[8][4];
#pragma unroll
    for (int i = 0; i < 8; ++i)
#pragma unroll
        for (int r = 0; r < 4; ++r)
            sxv[i][r] = sx[tileM + wm * 128 + i * 16 + quad * 4 + r];

#pragma unroll
    for (int j = 0; j < 4; ++j) {
        const int n = tileN + wn * 64 + j * 16 + l16;
        const float scn = scale[n];
        const float bsn = bias[n];
#pragma unroll
        for (int i = 0; i < 8; ++i) {
            const size_t mrow = (size_t)(tileM + wm * 128 + i * 16 + quad * 4);
#pragma unroll
            for (int r = 0; r < 4; ++r)
                y[(mrow + r) * NDIM + n] = (float)acc[i][j][r] * sxv[i][r] * scn + bsn;
        }
    }
#undef STAGE_A
#undef STAGE_B
#undef TILE
#undef VMW
}

// ---------------------------------------------------------------------------
extern "C" void kernel_launch(void* const* d_in, const int* in_sizes, int n_in,
                              void* d_out, int out_size, void* d_ws, size_t ws_size,
                              hipStream_t stream) {
    const float* x      = (const float*)d_in[0];   // [4,2048,4096] f32
    const int*   wdat   = (const int*)d_in[1];     // [16384,4096] int32 (int8 range)
    const float* scale  = (const float*)d_in[2];   // [16384,1]
    const float* bias   = (const float*)d_in[3];   // [16384]
    float* y = (float*)d_out;                      // [4,2048,16384] f32

    signed char* wq = (signed char*)d_ws;                       // N*K   = 64 MiB
    signed char* xq = wq + (size_t)NDIM * KDIM;                 // M*K   = 32 MiB
    float*       sx = (float*)(xq + (size_t)MDIM * KDIM);       // M*4   = 32 KiB

    conv_w<<<(NDIM * (size_t)KDIM) / 4 / 256, 256, 0, stream>>>((const int4*)wdat,
                                                                (int*)wq);
    quant_rows<<<MDIM, 256, 0, stream>>>(x, (int*)xq, sx);

    dim3 grid(NDIM / BN, MDIM / BM);   // (64, 32) = 2048 blocks
    gemm_i8<<<grid, 512, 0, stream>>>(xq, wq, sx, scale, bias, y);
}